// Round 6
// baseline (511.480 us; speedup 1.0000x reference)
//
#include <hip/hip_runtime.h>
#include <hip/hip_bf16.h>
#include <cstdint>

#define S_LEN 2048
#define HIDN  2048
#define NH    32
#define NKV   8
#define HD    64
#define FFN   8192
#define QKVN  3072   // 2048 q + 512 k + 512 v
#define QKVLD 3072

typedef __attribute__((ext_vector_type(4)))  float f32x4;
typedef __attribute__((ext_vector_type(16))) float f32x16;
typedef __attribute__((ext_vector_type(8)))  short short8;
typedef __attribute__((ext_vector_type(4)))  short s16x4;

__device__ __forceinline__ short f2bf(float f) {
  union { float f; uint32_t u; } v; v.f = f;
  uint32_t r = v.u + 0x7FFFu + ((v.u >> 16) & 1u);
  return (short)(r >> 16);
}
__device__ __forceinline__ float bf2f(short s) {
  union { float f; uint32_t u; } v; v.u = ((uint32_t)(uint16_t)s) << 16;
  return v.f;
}
__device__ __forceinline__ unsigned packbf2(float lo, float hi) {
  return (unsigned)(uint16_t)f2bf(lo) | ((unsigned)(uint16_t)f2bf(hi) << 16);
}

#define GLOAD_LDS16(gp, lp) \
  __builtin_amdgcn_global_load_lds((const __attribute__((address_space(1))) void*)(gp), \
                                   (__attribute__((address_space(3))) void*)(lp), 16, 0, 0)

#define BARRIER()  asm volatile("s_barrier" ::: "memory")
#define LGKM0()    asm volatile("s_waitcnt lgkmcnt(0)" ::: "memory")
#define SCHED0()   __builtin_amdgcn_sched_barrier(0)

// ---------------- transpose-convert: fp32 [K][N] -> bf16 [N][K] ----------------
__global__ __launch_bounds__(256) void convT_kernel(const float* __restrict__ src,
    short* __restrict__ dst, int K, int N) {
  __shared__ float t[64][65];
  const int k0 = blockIdx.x * 64, n0 = blockIdx.y * 64;
  const int tr = threadIdx.x >> 4, tc = (threadIdx.x & 15) * 4;
  #pragma unroll
  for (int i = 0; i < 4; ++i) {
    float4 v = *(const float4*)(src + (size_t)(k0 + tr + i * 16) * N + n0 + tc);
    t[tr + i * 16][tc] = v.x; t[tr + i * 16][tc + 1] = v.y;
    t[tr + i * 16][tc + 2] = v.z; t[tr + i * 16][tc + 3] = v.w;
  }
  __syncthreads();
  const int dr = threadIdx.x >> 2, dc = (threadIdx.x & 3) * 16;
  short8 o0, o1;
  #pragma unroll
  for (int j = 0; j < 8; ++j) { o0[j] = f2bf(t[dc + j][dr]); o1[j] = f2bf(t[dc + 8 + j][dr]); }
  short* dp = dst + (size_t)(n0 + dr) * K + k0 + dc;
  *(short8*)dp = o0;
  *(short8*)(dp + 8) = o1;
}

// ---------------- RMSNorm: fp32 in -> bf16 out ----------------
__global__ __launch_bounds__(256) void rmsnorm_kernel(const float* __restrict__ X,
    const float* __restrict__ W, short* __restrict__ Y) {
  int row = blockIdx.x;
  const float4* x4 = (const float4*)(X + (size_t)row * HIDN);
  const float4* w4 = (const float4*)W;
  float4 v0 = x4[2 * threadIdx.x];
  float4 v1 = x4[2 * threadIdx.x + 1];
  float ss = v0.x*v0.x + v0.y*v0.y + v0.z*v0.z + v0.w*v0.w
           + v1.x*v1.x + v1.y*v1.y + v1.z*v1.z + v1.w*v1.w;
  #pragma unroll
  for (int off = 32; off > 0; off >>= 1) ss += __shfl_xor(ss, off, 64);
  __shared__ float red[4];
  if ((threadIdx.x & 63) == 0) red[threadIdx.x >> 6] = ss;
  __syncthreads();
  ss = red[0] + red[1] + red[2] + red[3];
  float rs = rsqrtf(ss * (1.0f / HIDN) + 1e-5f);
  float4 w0 = w4[2 * threadIdx.x], w1 = w4[2 * threadIdx.x + 1];
  short8 o;
  o[0] = f2bf(v0.x * rs * w0.x); o[1] = f2bf(v0.y * rs * w0.y);
  o[2] = f2bf(v0.z * rs * w0.z); o[3] = f2bf(v0.w * rs * w0.w);
  o[4] = f2bf(v1.x * rs * w1.x); o[5] = f2bf(v1.y * rs * w1.y);
  o[6] = f2bf(v1.z * rs * w1.z); o[7] = f2bf(v1.w * rs * w1.w);
  *(short8*)(Y + (size_t)row * HIDN + threadIdx.x * 8) = o;
}

// ============ gemm8p: 256xBN tile, BK=64, 8 waves, 8-phase counted-vmcnt =====
// Phase=(mh,kk). Stage units A0/A1 (128 rows, 2 loads), B0/B1 (BN/2 rows, LB loads).
// Stage order per iter: B1(t+1) A1(t+1) A0(t+2) B0(t+2) | B1(t+2) A1(t+2) A0(t+3) B0(t+3)
// vmcnt(2+LB) at phases 4 and 8 only (never 0 in steady state).
// EPI 0: bf16=acc | 2: bf16=silu(Xbf16)*acc | 3: f32 partial at z*M*N
template<int EPI, int BN>
__global__ __launch_bounds__(512, 1) void gemm8p(const short* __restrict__ A,
    const short* __restrict__ BT, void* __restrict__ Cp, const void* __restrict__ Xp,
    int N, int Kfull, int KC, int gy) {
  constexpr int NFN = BN / 64;   // n-frags per wave
  constexpr int LB  = BN / 128;  // loads per B half-unit
  constexpr int VN  = 2 + LB;    // steady-state vmcnt
  __shared__ __align__(16) short As[2][256 * 64];
  __shared__ __align__(16) short Bs[2][BN * 64];
  const int tid = threadIdx.x, lane = tid & 63, w = tid >> 6;
  const int wm2 = w >> 2;                 // wave m-group (rows wm2*64 in each A-half)
  const int wn = (w & 3) * (BN / 4);      // wave n-base
  const int l15 = lane & 15, lg = lane >> 4;
  // XCD-aware decode: each XCD owns a contiguous chunk of bcol
  const int cpx = gy >> 3;
  const int xcd = blockIdx.x & 7, cid = blockIdx.x >> 3;
  const int by = xcd * cpx + cid % cpx, bx = cid / cpx;
  const int brow = bx * 256, bcol = by * BN;
  const size_t kbase = (size_t)blockIdx.z * KC;
  const int r8 = lane >> 3, c8 = lane & 7;
  const int gblk = c8 ^ r8;               // pre-swizzled source block (linear dest)
  const int nt = KC / 64;
  f32x4 acc[8][NFN] = {};
  short8 af[4], bf[2][NFN];

  auto STA = [&](int p, int kt, int h) {
    const size_t kc = kbase + (size_t)kt * 64 + gblk * 8;
    #pragma unroll
    for (int j = 0; j < 2; ++j) {
      const short* g = A + (size_t)(brow + h * 128 + j * 64 + w * 8 + r8) * Kfull + kc;
      GLOAD_LDS16(g, &As[p][(h * 128 + j * 64 + w * 8) * 64]);
    }
  };
  auto STB = [&](int p, int kt, int h) {
    const size_t kc = kbase + (size_t)kt * 64 + gblk * 8;
    #pragma unroll
    for (int j = 0; j < LB; ++j) {
      const short* g = BT + (size_t)(bcol + h * (BN / 2) + j * 64 + w * 8 + r8) * Kfull + kc;
      GLOAD_LDS16(g, &Bs[p][(h * (BN / 2) + j * 64 + w * 8) * 64]);
    }
  };
  auto LDA = [&](int p, int mh, int kk) {
    #pragma unroll
    for (int m = 0; m < 4; ++m) {
      const int row = mh * 128 + wm2 * 64 + m * 16 + l15;
      af[m] = *(const short8*)&As[p][row * 64 + (((kk * 4 + lg) ^ (row & 7)) * 8)];
    }
  };
  auto LDB = [&](int p, int kk) {
    #pragma unroll
    for (int n = 0; n < NFN; ++n) {
      const int row = wn + n * 16 + l15;
      bf[kk][n] = *(const short8*)&Bs[p][row * 64 + (((kk * 4 + lg) ^ (row & 7)) * 8)];
    }
  };

#define MMQ(MH, KK) \
  __builtin_amdgcn_s_setprio(1); \
  _Pragma("unroll") \
  for (int m = 0; m < 4; ++m) \
    _Pragma("unroll") \
    for (int n = 0; n < NFN; ++n) \
      acc[(MH) * 4 + m][n] = __builtin_amdgcn_mfma_f32_16x16x32_bf16(af[m], bf[KK][n], acc[(MH) * 4 + m][n], 0, 0, 0); \
  __builtin_amdgcn_s_setprio(0);

  // prologue: tile0 fully, tile1 A0+B0; wait for tile0 only
  STA(0, 0, 0); STB(0, 0, 0); STB(0, 0, 1); STA(0, 0, 1);
  STA(1, 1, 0); STB(1, 1, 0);
  asm volatile("s_waitcnt vmcnt(%0)" :: "n"(VN) : "memory");
  BARRIER();

  for (int i = 0; i < nt / 2; ++i) {
    const int t = 2 * i;
    const bool lastI = (i == nt / 2 - 1);
    // ph1 (buf0, mh0, k0) : stage B1(t+1)
    LDA(0, 0, 0); LDB(0, 0);
    STB(1, t + 1, 1);
    BARRIER(); LGKM0(); SCHED0();
    MMQ(0, 0);
    BARRIER();
    // ph2 (buf0, mh0, k1) : stage A1(t+1)
    LDA(0, 0, 1); LDB(0, 1);
    STA(1, t + 1, 1);
    BARRIER(); LGKM0(); SCHED0();
    MMQ(0, 1);
    BARRIER();
    // ph3 (buf0, mh1, k0) : stage A0(t+2)
    LDA(0, 1, 0);
    if (!lastI) STA(0, t + 2, 0);
    BARRIER(); LGKM0(); SCHED0();
    MMQ(1, 0);
    BARRIER();
    // ph4 (buf0, mh1, k1) : stage B0(t+2); vmcnt
    LDA(0, 1, 1);
    if (!lastI) STB(0, t + 2, 0);
    BARRIER(); LGKM0(); SCHED0();
    MMQ(1, 1);
    if (lastI) { asm volatile("s_waitcnt vmcnt(0)" ::: "memory"); }
    else       { asm volatile("s_waitcnt vmcnt(%0)" :: "n"(VN) : "memory"); }
    BARRIER();
    // ph5 (buf1, mh0, k0) : stage B1(t+2)
    LDA(1, 0, 0); LDB(1, 0);
    if (!lastI) STB(0, t + 2, 1);
    BARRIER(); LGKM0(); SCHED0();
    MMQ(0, 0);
    BARRIER();
    // ph6 (buf1, mh0, k1) : stage A1(t+2)
    LDA(1, 0, 1); LDB(1, 1);
    if (!lastI) STA(0, t + 2, 1);
    BARRIER(); LGKM0(); SCHED0();
    MMQ(0, 1);
    BARRIER();
    // ph7 (buf1, mh1, k0) : stage A0(t+3)
    LDA(1, 1, 0);
    if (!lastI) STA(1, t + 3, 0);
    BARRIER(); LGKM0(); SCHED0();
    MMQ(1, 0);
    BARRIER();
    // ph8 (buf1, mh1, k1) : stage B0(t+3); vmcnt
    LDA(1, 1, 1);
    if (!lastI) STB(1, t + 3, 0);
    BARRIER(); LGKM0(); SCHED0();
    MMQ(1, 1);
    if (!lastI) { asm volatile("s_waitcnt vmcnt(%0)" :: "n"(VN) : "memory"); }
    BARRIER();
  }
#undef MMQ

  #pragma unroll
  for (int mf = 0; mf < 8; ++mf) {
    const int r0 = brow + (mf >> 2) * 128 + wm2 * 64 + (mf & 3) * 16 + lg * 4;
    #pragma unroll
    for (int nf = 0; nf < NFN; ++nf) {
      const int c = bcol + wn + nf * 16 + l15;
      #pragma unroll
      for (int i4 = 0; i4 < 4; ++i4) {
        const size_t idx = (size_t)(r0 + i4) * N + c;
        float v = acc[mf][nf][i4];
        if (EPI == 0) ((short*)Cp)[idx] = f2bf(v);
        if (EPI == 2) {
          float gf = bf2f(((const short*)Xp)[idx]);
          ((short*)Cp)[idx] = f2bf(gf / (1.f + __expf(-gf)) * v);
        }
        if (EPI == 3) ((float*)Cp)[(size_t)blockIdx.z * S_LEN * N + idx] = v;
      }
    }
  }
}

// ---------------- GEMM 128x128 (WO): m97 structure ----------------
template<int EPI>
__global__ __launch_bounds__(256) void gemm_bt(const short* __restrict__ A,
    const short* __restrict__ BT, void* __restrict__ Cp, const void* __restrict__ Xp,
    int M, int N, int Kfull, int KC, int gx) {
  __shared__ __align__(16) short Ass[128 * 64];
  __shared__ __align__(16) short Bss[128 * 64];
  const int tid = threadIdx.x, lane = tid & 63, w = tid >> 6;
  const int wm = (w >> 1) * 64, wn = (w & 1) * 64;
  const int l15 = lane & 15, lg = lane >> 4;
  const int nwg = gridDim.x;
  const int qq = nwg >> 3, xcd = blockIdx.x & 7, off = blockIdx.x >> 3;
  const int wg = xcd * qq + off;
  const int brow = (wg % gx) * 128, bcol = (wg / gx) * 128;
  const size_t kbase = (size_t)blockIdx.y * KC;
  const int srow8 = lane >> 3;
  const int gblk  = (lane & 7) ^ (srow8 & 7);
  f32x4 acc[4][4] = {};

  for (int k0 = 0; k0 < KC; k0 += 64) {
    #pragma unroll
    for (int j = 0; j < 4; ++j) {
      const int rbase = w * 32 + j * 8;
      const int row = rbase + srow8;
      const short* ga = A + (size_t)(brow + row) * Kfull + kbase + k0 + gblk * 8;
      GLOAD_LDS16(ga, Ass + rbase * 64);
      const short* gb = BT + (size_t)(bcol + row) * Kfull + kbase + k0 + gblk * 8;
      GLOAD_LDS16(gb, Bss + rbase * 64);
    }
    __syncthreads();
    #pragma unroll
    for (int kk = 0; kk < 2; ++kk) {
      short8 af[4], bf[4];
      #pragma unroll
      for (int m = 0; m < 4; ++m) {
        const int row = wm + m * 16 + l15;
        af[m] = *(const short8*)&Ass[row * 64 + (((kk * 4 + lg) ^ (l15 & 7)) * 8)];
      }
      #pragma unroll
      for (int n = 0; n < 4; ++n) {
        const int row = wn + n * 16 + l15;
        bf[n] = *(const short8*)&Bss[row * 64 + (((kk * 4 + lg) ^ (l15 & 7)) * 8)];
      }
      #pragma unroll
      for (int m = 0; m < 4; ++m)
        #pragma unroll
        for (int n = 0; n < 4; ++n)
          acc[m][n] = __builtin_amdgcn_mfma_f32_16x16x32_bf16(af[m], bf[n], acc[m][n], 0, 0, 0);
    }
    __syncthreads();
  }

  const int r0 = brow + wm + lg * 4;
  const int c0 = bcol + wn + l15;
  #pragma unroll
  for (int m = 0; m < 4; ++m)
    #pragma unroll
    for (int n = 0; n < 4; ++n)
      #pragma unroll
      for (int i = 0; i < 4; ++i) {
        const size_t idx = (size_t)(r0 + m * 16 + i) * N + (c0 + n * 16);
        float v = acc[m][n][i];
        if (EPI == 0) ((short*)Cp)[idx] = f2bf(v);
        if (EPI == 1) ((float*)Cp)[idx] = v + ((const float*)Xp)[idx];
        if (EPI == 2) {
          float gf = bf2f(((const short*)Xp)[idx]);
          ((short*)Cp)[idx] = f2bf(gf / (1.f + __expf(-gf)) * v);
        }
        if (EPI == 3) ((float*)Cp)[(size_t)blockIdx.y * M * N + idx] = v;
      }
}

// ---------------- RoPE (in-place on bf16 qkv, q + k heads) ----------------
__global__ __launch_bounds__(256) void rope_kernel(short* __restrict__ qkv,
    const float* __restrict__ cosb, const float* __restrict__ sinb) {
  int idx = blockIdx.x * 256 + threadIdx.x;
  int d = idx & 31;
  int hh = (idx >> 5) % (NH + NKV);
  int s = idx / (32 * (NH + NKV));
  int col = (hh < NH) ? hh * HD : HIDN + (hh - NH) * HD;
  short* base = qkv + (size_t)s * QKVLD + col;
  float c  = cosb[s * HD + d];
  float sn = sinb[s * HD + d];
  float x1 = bf2f(base[d]), x2 = bf2f(base[d + 32]);
  base[d]      = f2bf(x1 * c - x2 * sn);
  base[d + 32] = f2bf(x2 * c + x1 * sn);
}

// ---------------- Flash attention: swapped-operand 32x32x16 structure --------
__global__ __launch_bounds__(256) void attn_kernel(const short* __restrict__ QKV,
    short* __restrict__ O) {
  __shared__ __align__(16) short Ks[64][72];
  __shared__ __align__(16) short VTs[64][72];
  const int bid = blockIdx.x;
  const int half = bid >> 8, idx = bid & 255;
  const int h = idx & 31;
  int qt = idx >> 5;
  qt = half ? (15 - qt) : qt;
  const int kvh = h >> 2;
  const int tid = threadIdx.x, lane = tid & 63, w = tid >> 6;
  const int l31 = lane & 31, hi = lane >> 5;
  const int qb = qt * 128 + w * 32;
  const int kcol = HIDN + kvh * HD;
  const int vcol = HIDN + NKV * HD + kvh * HD;

  short8 Qr[4];
  {
    const short* qp = QKV + (size_t)(qb + l31) * QKVLD + h * HD;
    #pragma unroll
    for (int dk = 0; dk < 4; ++dk) {
      short8 qv = *(const short8*)(qp + dk * 16 + hi * 8);
      #pragma unroll
      for (int e = 0; e < 8; ++e) Qr[dk][e] = f2bf(bf2f(qv[e]) * 0.125f);
    }
  }
  float m_ = -3e38f, l_ = 0.f;
  f32x16 o0 = {}, o1 = {};
  const int nt = 2 * qt + 2;
  const int krow = tid >> 2, kcb = (tid & 3) * 16;
  const int vk = tid & 31, vdb = (tid >> 5) * 8;

  for (int t = 0; t < nt; ++t) {
    const int kb = t * 64;
    __syncthreads();
    {
      const short* gk = QKV + (size_t)(kb + krow) * QKVLD + kcol + kcb;
      short8 a = *(const short8*)gk;
      short8 b = *(const short8*)(gk + 8);
      *(short8*)&Ks[krow][kcb] = a;
      *(short8*)&Ks[krow][kcb + 8] = b;
    }
    #pragma unroll
    for (int i = 0; i < 2; ++i) {
      const int k = i * 32 + vk;
      short8 v = *(const short8*)(QKV + (size_t)(kb + k) * QKVLD + vcol + vdb);
      #pragma unroll
      for (int j = 0; j < 8; ++j) VTs[vdb + j][k] = v[j];
    }
    __syncthreads();
    if (kb < qb + 32) {
      f32x16 s[2] = {};
      #pragma unroll
      for (int kt = 0; kt < 2; ++kt)
        #pragma unroll
        for (int dk = 0; dk < 4; ++dk) {
          short8 kf = *(const short8*)&Ks[kt * 32 + l31][dk * 16 + hi * 8];
          s[kt] = __builtin_amdgcn_mfma_f32_32x32x16_bf16(kf, Qr[dk], s[kt], 0, 0, 0);
        }
      if (kb + 63 > qb) {
        const int qg = qb + l31;
        #pragma unroll
        for (int kt = 0; kt < 2; ++kt)
          #pragma unroll
          for (int r = 0; r < 16; ++r) {
            const int kg = kb + kt * 32 + (r & 3) + 8 * (r >> 2) + 4 * hi;
            if (kg > qg) s[kt][r] = -1e30f;
          }
      }
      float pm = s[0][0];
      #pragma unroll
      for (int r = 1; r < 16; ++r) pm = fmaxf(pm, s[0][r]);
      #pragma unroll
      for (int r = 0; r < 16; ++r) pm = fmaxf(pm, s[1][r]);
      pm = fmaxf(pm, __shfl_xor(pm, 32));
      const float mn = fmaxf(m_, pm);
      const float al = __expf(m_ - mn);
      float rsum = 0.f;
      #pragma unroll
      for (int kt = 0; kt < 2; ++kt)
        #pragma unroll
        for (int r = 0; r < 16; ++r) { s[kt][r] = __expf(s[kt][r] - mn); rsum += s[kt][r]; }
      rsum += __shfl_xor(rsum, 32);
      l_ = l_ * al + rsum;
      m_ = mn;
      o0 *= al; o1 *= al;
      unsigned wd[2][8], rw[2][8];
      #pragma unroll
      for (int kt = 0; kt < 2; ++kt)
        #pragma unroll
        for (int i = 0; i < 8; ++i) {
          wd[kt][i] = packbf2(s[kt][2 * i], s[kt][2 * i + 1]);
          rw[kt][i] = (unsigned)__shfl_xor((int)wd[kt][i], 32);
        }
      #pragma unroll
      for (int kt = 0; kt < 2; ++kt) {
        union { unsigned u[4]; short8 s8; } pf0, pf1;
        if (hi) {
          pf0.u[0] = rw[kt][2]; pf0.u[1] = rw[kt][3]; pf0.u[2] = wd[kt][2]; pf0.u[3] = wd[kt][3];
          pf1.u[0] = rw[kt][6]; pf1.u[1] = rw[kt][7]; pf1.u[2] = wd[kt][6]; pf1.u[3] = wd[kt][7];
        } else {
          pf0.u[0] = wd[kt][0]; pf0.u[1] = wd[kt][1]; pf0.u[2] = rw[kt][0]; pf0.u[3] = rw[kt][1];
          pf1.u[0] = wd[kt][4]; pf1.u[1] = wd[kt][5]; pf1.u[2] = rw[kt][4]; pf1.u[3] = rw[kt][5];
        }
        #pragma unroll
        for (int ks = 0; ks < 2; ++ks) {
          const short8 pB = ks ? pf1.s8 : pf0.s8;
          short8 va = *(const short8*)&VTs[l31][kt * 32 + ks * 16 + hi * 8];
          o0 = __builtin_amdgcn_mfma_f32_32x32x16_bf16(va, pB, o0, 0, 0, 0);
          short8 vb = *(const short8*)&VTs[32 + l31][kt * 32 + ks * 16 + hi * 8];
          o1 = __builtin_amdgcn_mfma_f32_32x32x16_bf16(vb, pB, o1, 0, 0, 0);
        }
      }
    }
  }
  const float inv = 1.f / l_;
  short* op = O + (size_t)(qb + l31) * HIDN + h * HD;
  #pragma unroll
  for (int dt = 0; dt < 2; ++dt) {
    const f32x16& o = dt ? o1 : o0;
    #pragma unroll
    for (int g = 0; g < 4; ++g) {
      s16x4 st;
      st[0] = f2bf(o[g * 4 + 0] * inv);
      st[1] = f2bf(o[g * 4 + 1] * inv);
      st[2] = f2bf(o[g * 4 + 2] * inv);
      st[3] = f2bf(o[g * 4 + 3] * inv);
      *(s16x4*)(op + dt * 32 + g * 8 + hi * 4) = st;
    }
  }
}

// ---------------- out += P0 + P1 (split-K reduce) ----------------
__global__ __launch_bounds__(256) void reduce_kernel(float* __restrict__ out,
    const float* __restrict__ P) {
  const size_t n = (size_t)S_LEN * HIDN;
  size_t i = ((size_t)blockIdx.x * 256 + threadIdx.x) * 4;
  float4 o = *(float4*)(out + i);
  float4 a = *(const float4*)(P + i);
  float4 b = *(const float4*)(P + n + i);
  o.x += a.x + b.x; o.y += a.y + b.y; o.z += a.z + b.z; o.w += a.w + b.w;
  *(float4*)(out + i) = o;
}

extern "C" void kernel_launch(void* const* d_in, const int* in_sizes, int n_in,
                              void* d_out, int out_size, void* d_ws, size_t ws_size,
                              hipStream_t stream) {
  const float* hs   = (const float*)d_in[0];
  const float* cosb = (const float*)d_in[1];
  const float* sinb = (const float*)d_in[2];
  const float* wq   = (const float*)d_in[3];
  const float* wk   = (const float*)d_in[4];
  const float* wv   = (const float*)d_in[5];
  const float* wo   = (const float*)d_in[6];
  const float* wln1 = (const float*)d_in[7];
  const float* wln2 = (const float*)d_in[8];
  const float* wg   = (const float*)d_in[9];
  const float* wu   = (const float*)d_in[10];
  const float* wd   = (const float*)d_in[11];
  float* out = (float*)d_out;
  char* ws = (char*)d_ws;
  const size_t MB = 1024 * 1024;
  short* xn    = (short*)(ws);             //  8 MB bf16 [2048][2048]
  short* y     = (short*)(ws + 8 * MB);    //  8 MB
  short* attnO = (short*)(ws + 16 * MB);   //  8 MB
  short* qkv   = (short*)(ws + 24 * MB);   // 12.6 MB bf16 [2048][3072]
  short* g     = (short*)(ws + 37 * MB);   // 32 MB bf16 [2048][8192]
  short* Wbuf  = (short*)(ws + 69 * MB);   // 32 MB time-shared transposed weights
  float* P     = (float*)(ws);             // 32 MB split-K partials (aliases dead bufs)

  convT_kernel<<<dim3(32, 32), 256, 0, stream>>>(wq, Wbuf, HIDN, NH * HD);
  convT_kernel<<<dim3(32, 8),  256, 0, stream>>>(wk, Wbuf + (size_t)2048 * HIDN, HIDN, NKV * HD);
  convT_kernel<<<dim3(32, 8),  256, 0, stream>>>(wv, Wbuf + (size_t)2560 * HIDN, HIDN, NKV * HD);
  rmsnorm_kernel<<<S_LEN, 256, 0, stream>>>(hs, wln1, xn);
  gemm8p<0, 128><<<dim3(192, 1, 1), 512, 0, stream>>>(xn, Wbuf, qkv, nullptr, QKVN, HIDN, HIDN, 24);
  convT_kernel<<<dim3(32, 32), 256, 0, stream>>>(wo, Wbuf, NH * HD, HIDN);
  rope_kernel<<<(S_LEN * (NH + NKV) * 32) / 256, 256, 0, stream>>>(qkv, cosb, sinb);
  attn_kernel<<<NH * (S_LEN / 128), 256, 0, stream>>>(qkv, attnO);
  gemm_bt<1><<<dim3(16 * 16, 1), 256, 0, stream>>>(attnO, Wbuf, out, hs, S_LEN, HIDN, NH * HD, NH * HD, 16);
  rmsnorm_kernel<<<S_LEN, 256, 0, stream>>>(out, wln2, y);
  convT_kernel<<<dim3(32, 128), 256, 0, stream>>>(wg, Wbuf, HIDN, FFN);
  gemm8p<0, 256><<<dim3(256, 1, 1), 512, 0, stream>>>(y, Wbuf, g, nullptr, FFN, HIDN, HIDN, 32);
  convT_kernel<<<dim3(32, 128), 256, 0, stream>>>(wu, Wbuf, HIDN, FFN);
  gemm8p<2, 256><<<dim3(256, 1, 1), 512, 0, stream>>>(y, Wbuf, g, g, FFN, HIDN, HIDN, 32);
  convT_kernel<<<dim3(128, 32), 256, 0, stream>>>(wd, Wbuf, FFN, HIDN);
  gemm8p<3, 128><<<dim3(128, 1, 2), 512, 0, stream>>>(g, Wbuf, P, nullptr, HIDN, FFN, FFN / 2, 16);
  reduce_kernel<<<(S_LEN * HIDN) / 1024, 256, 0, stream>>>(out, P);
}

// Round 7
// 463.712 us; speedup vs baseline: 1.1030x; 1.1030x over previous
//
#include <hip/hip_runtime.h>
#include <hip/hip_bf16.h>
#include <cstdint>

#define S_LEN 2048
#define HIDN  2048
#define NH    32
#define NKV   8
#define HD    64
#define FFN   8192
#define QKVN  3072   // 2048 q + 512 k + 512 v
#define QKVLD 3072

typedef __attribute__((ext_vector_type(4)))  float f32x4;
typedef __attribute__((ext_vector_type(16))) float f32x16;
typedef __attribute__((ext_vector_type(8)))  short short8;
typedef __attribute__((ext_vector_type(4)))  short s16x4;

__device__ __forceinline__ short f2bf(float f) {
  union { float f; uint32_t u; } v; v.f = f;
  uint32_t r = v.u + 0x7FFFu + ((v.u >> 16) & 1u);
  return (short)(r >> 16);
}
__device__ __forceinline__ float bf2f(short s) {
  union { float f; uint32_t u; } v; v.u = ((uint32_t)(uint16_t)s) << 16;
  return v.f;
}
__device__ __forceinline__ unsigned packbf2(float lo, float hi) {
  return (unsigned)(uint16_t)f2bf(lo) | ((unsigned)(uint16_t)f2bf(hi) << 16);
}

#define GLOAD_LDS16(gp, lp) \
  __builtin_amdgcn_global_load_lds((const __attribute__((address_space(1))) void*)(gp), \
                                   (__attribute__((address_space(3))) void*)(lp), 16, 0, 0)

#define BARRIER()  asm volatile("s_barrier" ::: "memory")
#define LGKM0()    asm volatile("s_waitcnt lgkmcnt(0)" ::: "memory")
#define SCHED0()   __builtin_amdgcn_sched_barrier(0)
#define VMCNT(N)   asm volatile("s_waitcnt vmcnt(%0)" :: "n"(N) : "memory")

// ---------------- transpose-convert: fp32 [K][N] -> bf16 [N][K] ----------------
__global__ __launch_bounds__(256) void convT_kernel(const float* __restrict__ src,
    short* __restrict__ dst, int K, int N) {
  __shared__ float t[64][65];
  const int k0 = blockIdx.x * 64, n0 = blockIdx.y * 64;
  const int tr = threadIdx.x >> 4, tc = (threadIdx.x & 15) * 4;
  #pragma unroll
  for (int i = 0; i < 4; ++i) {
    float4 v = *(const float4*)(src + (size_t)(k0 + tr + i * 16) * N + n0 + tc);
    t[tr + i * 16][tc] = v.x; t[tr + i * 16][tc + 1] = v.y;
    t[tr + i * 16][tc + 2] = v.z; t[tr + i * 16][tc + 3] = v.w;
  }
  __syncthreads();
  const int dr = threadIdx.x >> 2, dc = (threadIdx.x & 3) * 16;
  short8 o0, o1;
  #pragma unroll
  for (int j = 0; j < 8; ++j) { o0[j] = f2bf(t[dc + j][dr]); o1[j] = f2bf(t[dc + 8 + j][dr]); }
  short* dp = dst + (size_t)(n0 + dr) * K + k0 + dc;
  *(short8*)dp = o0;
  *(short8*)(dp + 8) = o1;
}

// ---------------- RMSNorm: fp32 in -> bf16 out ----------------
__global__ __launch_bounds__(256) void rmsnorm_kernel(const float* __restrict__ X,
    const float* __restrict__ W, short* __restrict__ Y) {
  int row = blockIdx.x;
  const float4* x4 = (const float4*)(X + (size_t)row * HIDN);
  const float4* w4 = (const float4*)W;
  float4 v0 = x4[2 * threadIdx.x];
  float4 v1 = x4[2 * threadIdx.x + 1];
  float ss = v0.x*v0.x + v0.y*v0.y + v0.z*v0.z + v0.w*v0.w
           + v1.x*v1.x + v1.y*v1.y + v1.z*v1.z + v1.w*v1.w;
  #pragma unroll
  for (int off = 32; off > 0; off >>= 1) ss += __shfl_xor(ss, off, 64);
  __shared__ float red[4];
  if ((threadIdx.x & 63) == 0) red[threadIdx.x >> 6] = ss;
  __syncthreads();
  ss = red[0] + red[1] + red[2] + red[3];
  float rs = rsqrtf(ss * (1.0f / HIDN) + 1e-5f);
  float4 w0 = w4[2 * threadIdx.x], w1 = w4[2 * threadIdx.x + 1];
  short8 o;
  o[0] = f2bf(v0.x * rs * w0.x); o[1] = f2bf(v0.y * rs * w0.y);
  o[2] = f2bf(v0.z * rs * w0.z); o[3] = f2bf(v0.w * rs * w0.w);
  o[4] = f2bf(v1.x * rs * w1.x); o[5] = f2bf(v1.y * rs * w1.y);
  o[6] = f2bf(v1.z * rs * w1.z); o[7] = f2bf(v1.w * rs * w1.w);
  *(short8*)(Y + (size_t)row * HIDN + threadIdx.x * 8) = o;
}

// ============ gemm8p: 256xBN tile, BK=64, 8 waves, 8-phase depth-3 pipeline ==
// Units per tile: A0 (rows 0-127, 2 loads), A1 (128-255, 2), B0 (BN/2, LB), B1 (LB).
// B k0+k1 fragments both loaded at ph1/ph5 (B-LDS free after one phase).
// Steady stage order: ph1:A1(t+1) ph2:B0(t+2) ph3:B1(t+2) ph4:A0(t+2)
//                     ph5:A1(t+2) ph6:B0(t+3) ph7:B1(t+3) ph8:A0(t+3)
// vmcnt(VN=2+2LB) at ph4/ph8 only => 3 units stay in flight; all reads' units
// are >=4 units older than the wait => retired (in-order vmcnt retirement).
// EPI 0: bf16=acc | 2: bf16=silu(Xbf16)*acc | 3: f32 partial at z*M*N
template<int EPI, int BN>
__global__ __launch_bounds__(512, 1) void gemm8p(const short* __restrict__ A,
    const short* __restrict__ BT, void* __restrict__ Cp, const void* __restrict__ Xp,
    int N, int Kfull, int KC, int gy) {
  constexpr int NFN = BN / 64;   // n-frags per wave
  constexpr int LB  = BN / 128;  // loads per B half-unit
  constexpr int VN  = 2 + 2 * LB;
  __shared__ __align__(16) short As[2][256 * 64];
  __shared__ __align__(16) short Bs[2][BN * 64];
  const int tid = threadIdx.x, lane = tid & 63, w = tid >> 6;
  const int wm2 = w >> 2;
  const int wn = (w & 3) * (BN / 4);
  const int l15 = lane & 15, lg = lane >> 4;
  const int cpx = gy >> 3;
  const int xcd = blockIdx.x & 7, cid = blockIdx.x >> 3;
  const int by = xcd * cpx + cid % cpx, bx = cid / cpx;
  const int brow = bx * 256, bcol = by * BN;
  const size_t kbase = (size_t)blockIdx.z * KC;
  const int r8 = lane >> 3, c8 = lane & 7;
  const int gblk = c8 ^ r8;
  const int nt = KC / 64;
  f32x4 acc[8][NFN] = {};
  short8 af[4], bf[2][NFN];

  auto STA = [&](int p, int kt, int h) {
    const size_t kc = kbase + (size_t)kt * 64 + gblk * 8;
    #pragma unroll
    for (int j = 0; j < 2; ++j) {
      const short* g = A + (size_t)(brow + h * 128 + j * 64 + w * 8 + r8) * Kfull + kc;
      GLOAD_LDS16(g, &As[p][(h * 128 + j * 64 + w * 8) * 64]);
    }
  };
  auto STB = [&](int p, int kt, int h) {
    const size_t kc = kbase + (size_t)kt * 64 + gblk * 8;
    #pragma unroll
    for (int j = 0; j < LB; ++j) {
      const short* g = BT + (size_t)(bcol + h * (BN / 2) + j * 64 + w * 8 + r8) * Kfull + kc;
      GLOAD_LDS16(g, &Bs[p][(h * (BN / 2) + j * 64 + w * 8) * 64]);
    }
  };
  auto LDA = [&](int p, int mh, int kk) {
    #pragma unroll
    for (int m = 0; m < 4; ++m) {
      const int row = mh * 128 + wm2 * 64 + m * 16 + l15;
      af[m] = *(const short8*)&As[p][row * 64 + (((kk * 4 + lg) ^ (row & 7)) * 8)];
    }
  };
  auto LDB = [&](int p, int kk) {
    #pragma unroll
    for (int n = 0; n < NFN; ++n) {
      const int row = wn + n * 16 + l15;
      bf[kk][n] = *(const short8*)&Bs[p][row * 64 + (((kk * 4 + lg) ^ (row & 7)) * 8)];
    }
  };

#define MMQ(MH, KK) \
  __builtin_amdgcn_s_setprio(1); \
  _Pragma("unroll") \
  for (int m = 0; m < 4; ++m) \
    _Pragma("unroll") \
    for (int n = 0; n < NFN; ++n) \
      acc[(MH) * 4 + m][n] = __builtin_amdgcn_mfma_f32_16x16x32_bf16(af[m], bf[KK][n], acc[(MH) * 4 + m][n], 0, 0, 0); \
  __builtin_amdgcn_s_setprio(0);

  // prologue: T0 fully (B0,B1,A0,A1), T1 partial (B0,B1,A0); wait T0 only
  STB(0, 0, 0); STB(0, 0, 1); STA(0, 0, 0); STA(0, 0, 1);
  STB(1, 1, 0); STB(1, 1, 1); STA(1, 1, 0);
  VMCNT(VN);
  BARRIER();

  for (int i = 0; i < nt / 2; ++i) {
    const int t = 2 * i;
    const bool li = (i == nt / 2 - 1);
    // ph1: read buf0 {A0 k0, B k0+k1}; stage A1(t+1)
    LDA(0, 0, 0); LDB(0, 0); LDB(0, 1);
    STA(1, t + 1, 1);
    BARRIER(); LGKM0(); SCHED0();
    MMQ(0, 0);
    BARRIER();
    // ph2: read A0 k1; stage B0(t+2)
    LDA(0, 0, 1);
    if (!li) STB(0, t + 2, 0);
    BARRIER(); LGKM0(); SCHED0();
    MMQ(0, 1);
    BARRIER();
    // ph3: read A1 k0; stage B1(t+2)
    LDA(0, 1, 0);
    if (!li) STB(0, t + 2, 1);
    BARRIER(); LGKM0(); SCHED0();
    MMQ(1, 0);
    BARRIER();
    // ph4: read A1 k1; stage A0(t+2); vmcnt
    LDA(0, 1, 1);
    if (!li) STA(0, t + 2, 0);
    BARRIER(); LGKM0(); SCHED0();
    MMQ(1, 1);
    if (li) { VMCNT(0); } else { VMCNT(VN); }
    BARRIER();
    // ph5: read buf1 {A0 k0, B k0+k1}; stage A1(t+2)
    LDA(1, 0, 0); LDB(1, 0); LDB(1, 1);
    if (!li) STA(0, t + 2, 1);
    BARRIER(); LGKM0(); SCHED0();
    MMQ(0, 0);
    BARRIER();
    // ph6: read A0 k1; stage B0(t+3)
    LDA(1, 0, 1);
    if (!li) STB(1, t + 3, 0);
    BARRIER(); LGKM0(); SCHED0();
    MMQ(0, 1);
    BARRIER();
    // ph7: read A1 k0; stage B1(t+3)
    LDA(1, 1, 0);
    if (!li) STB(1, t + 3, 1);
    BARRIER(); LGKM0(); SCHED0();
    MMQ(1, 0);
    BARRIER();
    // ph8: read A1 k1; stage A0(t+3); vmcnt
    LDA(1, 1, 1);
    if (!li) STA(1, t + 3, 0);
    BARRIER(); LGKM0(); SCHED0();
    MMQ(1, 1);
    if (!li) { VMCNT(VN); }
    BARRIER();
  }
#undef MMQ

  #pragma unroll
  for (int mf = 0; mf < 8; ++mf) {
    const int r0 = brow + (mf >> 2) * 128 + wm2 * 64 + (mf & 3) * 16 + lg * 4;
    #pragma unroll
    for (int nf = 0; nf < NFN; ++nf) {
      const int c = bcol + wn + nf * 16 + l15;
      #pragma unroll
      for (int i4 = 0; i4 < 4; ++i4) {
        const size_t idx = (size_t)(r0 + i4) * N + c;
        float v = acc[mf][nf][i4];
        if (EPI == 0) ((short*)Cp)[idx] = f2bf(v);
        if (EPI == 2) {
          float gf = bf2f(((const short*)Xp)[idx]);
          ((short*)Cp)[idx] = f2bf(gf / (1.f + __expf(-gf)) * v);
        }
        if (EPI == 3) ((float*)Cp)[(size_t)blockIdx.z * S_LEN * N + idx] = v;
      }
    }
  }
}

// ---------------- GEMM 128x128 (WO): m97 structure ----------------
template<int EPI>
__global__ __launch_bounds__(256) void gemm_bt(const short* __restrict__ A,
    const short* __restrict__ BT, void* __restrict__ Cp, const void* __restrict__ Xp,
    int M, int N, int Kfull, int KC, int gx) {
  __shared__ __align__(16) short Ass[128 * 64];
  __shared__ __align__(16) short Bss[128 * 64];
  const int tid = threadIdx.x, lane = tid & 63, w = tid >> 6;
  const int wm = (w >> 1) * 64, wn = (w & 1) * 64;
  const int l15 = lane & 15, lg = lane >> 4;
  const int nwg = gridDim.x;
  const int qq = nwg >> 3, xcd = blockIdx.x & 7, off = blockIdx.x >> 3;
  const int wg = xcd * qq + off;
  const int brow = (wg % gx) * 128, bcol = (wg / gx) * 128;
  const size_t kbase = (size_t)blockIdx.y * KC;
  const int srow8 = lane >> 3;
  const int gblk  = (lane & 7) ^ (srow8 & 7);
  f32x4 acc[4][4] = {};

  for (int k0 = 0; k0 < KC; k0 += 64) {
    #pragma unroll
    for (int j = 0; j < 4; ++j) {
      const int rbase = w * 32 + j * 8;
      const int row = rbase + srow8;
      const short* ga = A + (size_t)(brow + row) * Kfull + kbase + k0 + gblk * 8;
      GLOAD_LDS16(ga, Ass + rbase * 64);
      const short* gb = BT + (size_t)(bcol + row) * Kfull + kbase + k0 + gblk * 8;
      GLOAD_LDS16(gb, Bss + rbase * 64);
    }
    __syncthreads();
    #pragma unroll
    for (int kk = 0; kk < 2; ++kk) {
      short8 af[4], bf[4];
      #pragma unroll
      for (int m = 0; m < 4; ++m) {
        const int row = wm + m * 16 + l15;
        af[m] = *(const short8*)&Ass[row * 64 + (((kk * 4 + lg) ^ (l15 & 7)) * 8)];
      }
      #pragma unroll
      for (int n = 0; n < 4; ++n) {
        const int row = wn + n * 16 + l15;
        bf[n] = *(const short8*)&Bss[row * 64 + (((kk * 4 + lg) ^ (l15 & 7)) * 8)];
      }
      #pragma unroll
      for (int m = 0; m < 4; ++m)
        #pragma unroll
        for (int n = 0; n < 4; ++n)
          acc[m][n] = __builtin_amdgcn_mfma_f32_16x16x32_bf16(af[m], bf[n], acc[m][n], 0, 0, 0);
    }
    __syncthreads();
  }

  const int r0 = brow + wm + lg * 4;
  const int c0 = bcol + wn + l15;
  #pragma unroll
  for (int m = 0; m < 4; ++m)
    #pragma unroll
    for (int n = 0; n < 4; ++n)
      #pragma unroll
      for (int i = 0; i < 4; ++i) {
        const size_t idx = (size_t)(r0 + m * 16 + i) * N + (c0 + n * 16);
        float v = acc[m][n][i];
        if (EPI == 0) ((short*)Cp)[idx] = f2bf(v);
        if (EPI == 1) ((float*)Cp)[idx] = v + ((const float*)Xp)[idx];
        if (EPI == 2) {
          float gf = bf2f(((const short*)Xp)[idx]);
          ((short*)Cp)[idx] = f2bf(gf / (1.f + __expf(-gf)) * v);
        }
        if (EPI == 3) ((float*)Cp)[(size_t)blockIdx.y * M * N + idx] = v;
      }
}

// ---------------- RoPE (in-place on bf16 qkv, q + k heads) ----------------
__global__ __launch_bounds__(256) void rope_kernel(short* __restrict__ qkv,
    const float* __restrict__ cosb, const float* __restrict__ sinb) {
  int idx = blockIdx.x * 256 + threadIdx.x;
  int d = idx & 31;
  int hh = (idx >> 5) % (NH + NKV);
  int s = idx / (32 * (NH + NKV));
  int col = (hh < NH) ? hh * HD : HIDN + (hh - NH) * HD;
  short* base = qkv + (size_t)s * QKVLD + col;
  float c  = cosb[s * HD + d];
  float sn = sinb[s * HD + d];
  float x1 = bf2f(base[d]), x2 = bf2f(base[d + 32]);
  base[d]      = f2bf(x1 * c - x2 * sn);
  base[d + 32] = f2bf(x2 * c + x1 * sn);
}

// ---------------- Flash attention: swapped-operand 32x32x16 structure --------
__global__ __launch_bounds__(256) void attn_kernel(const short* __restrict__ QKV,
    short* __restrict__ O) {
  __shared__ __align__(16) short Ks[64][72];
  __shared__ __align__(16) short VTs[64][72];
  const int bid = blockIdx.x;
  const int half = bid >> 8, idx = bid & 255;
  const int h = idx & 31;
  int qt = idx >> 5;
  qt = half ? (15 - qt) : qt;
  const int kvh = h >> 2;
  const int tid = threadIdx.x, lane = tid & 63, w = tid >> 6;
  const int l31 = lane & 31, hi = lane >> 5;
  const int qb = qt * 128 + w * 32;
  const int kcol = HIDN + kvh * HD;
  const int vcol = HIDN + NKV * HD + kvh * HD;

  short8 Qr[4];
  {
    const short* qp = QKV + (size_t)(qb + l31) * QKVLD + h * HD;
    #pragma unroll
    for (int dk = 0; dk < 4; ++dk) {
      short8 qv = *(const short8*)(qp + dk * 16 + hi * 8);
      #pragma unroll
      for (int e = 0; e < 8; ++e) Qr[dk][e] = f2bf(bf2f(qv[e]) * 0.125f);
    }
  }
  float m_ = -3e38f, l_ = 0.f;
  f32x16 o0 = {}, o1 = {};
  const int nt = 2 * qt + 2;
  const int krow = tid >> 2, kcb = (tid & 3) * 16;
  const int vk = tid & 31, vdb = (tid >> 5) * 8;

  for (int t = 0; t < nt; ++t) {
    const int kb = t * 64;
    __syncthreads();
    {
      const short* gk = QKV + (size_t)(kb + krow) * QKVLD + kcol + kcb;
      short8 a = *(const short8*)gk;
      short8 b = *(const short8*)(gk + 8);
      *(short8*)&Ks[krow][kcb] = a;
      *(short8*)&Ks[krow][kcb + 8] = b;
    }
    #pragma unroll
    for (int i = 0; i < 2; ++i) {
      const int k = i * 32 + vk;
      short8 v = *(const short8*)(QKV + (size_t)(kb + k) * QKVLD + vcol + vdb);
      #pragma unroll
      for (int j = 0; j < 8; ++j) VTs[vdb + j][k] = v[j];
    }
    __syncthreads();
    if (kb < qb + 32) {
      f32x16 s[2] = {};
      #pragma unroll
      for (int kt = 0; kt < 2; ++kt)
        #pragma unroll
        for (int dk = 0; dk < 4; ++dk) {
          short8 kf = *(const short8*)&Ks[kt * 32 + l31][dk * 16 + hi * 8];
          s[kt] = __builtin_amdgcn_mfma_f32_32x32x16_bf16(kf, Qr[dk], s[kt], 0, 0, 0);
        }
      if (kb + 63 > qb) {
        const int qg = qb + l31;
        #pragma unroll
        for (int kt = 0; kt < 2; ++kt)
          #pragma unroll
          for (int r = 0; r < 16; ++r) {
            const int kg = kb + kt * 32 + (r & 3) + 8 * (r >> 2) + 4 * hi;
            if (kg > qg) s[kt][r] = -1e30f;
          }
      }
      float pm = s[0][0];
      #pragma unroll
      for (int r = 1; r < 16; ++r) pm = fmaxf(pm, s[0][r]);
      #pragma unroll
      for (int r = 0; r < 16; ++r) pm = fmaxf(pm, s[1][r]);
      pm = fmaxf(pm, __shfl_xor(pm, 32));
      const float mn = fmaxf(m_, pm);
      const float al = __expf(m_ - mn);
      float rsum = 0.f;
      #pragma unroll
      for (int kt = 0; kt < 2; ++kt)
        #pragma unroll
        for (int r = 0; r < 16; ++r) { s[kt][r] = __expf(s[kt][r] - mn); rsum += s[kt][r]; }
      rsum += __shfl_xor(rsum, 32);
      l_ = l_ * al + rsum;
      m_ = mn;
      o0 *= al; o1 *= al;
      unsigned wd[2][8], rw[2][8];
      #pragma unroll
      for (int kt = 0; kt < 2; ++kt)
        #pragma unroll
        for (int i = 0; i < 8; ++i) {
          wd[kt][i] = packbf2(s[kt][2 * i], s[kt][2 * i + 1]);
          rw[kt][i] = (unsigned)__shfl_xor((int)wd[kt][i], 32);
        }
      #pragma unroll
      for (int kt = 0; kt < 2; ++kt) {
        union { unsigned u[4]; short8 s8; } pf0, pf1;
        if (hi) {
          pf0.u[0] = rw[kt][2]; pf0.u[1] = rw[kt][3]; pf0.u[2] = wd[kt][2]; pf0.u[3] = wd[kt][3];
          pf1.u[0] = rw[kt][6]; pf1.u[1] = rw[kt][7]; pf1.u[2] = wd[kt][6]; pf1.u[3] = wd[kt][7];
        } else {
          pf0.u[0] = wd[kt][0]; pf0.u[1] = wd[kt][1]; pf0.u[2] = rw[kt][0]; pf0.u[3] = rw[kt][1];
          pf1.u[0] = wd[kt][4]; pf1.u[1] = wd[kt][5]; pf1.u[2] = rw[kt][4]; pf1.u[3] = rw[kt][5];
        }
        #pragma unroll
        for (int ks = 0; ks < 2; ++ks) {
          const short8 pB = ks ? pf1.s8 : pf0.s8;
          short8 va = *(const short8*)&VTs[l31][kt * 32 + ks * 16 + hi * 8];
          o0 = __builtin_amdgcn_mfma_f32_32x32x16_bf16(va, pB, o0, 0, 0, 0);
          short8 vb = *(const short8*)&VTs[32 + l31][kt * 32 + ks * 16 + hi * 8];
          o1 = __builtin_amdgcn_mfma_f32_32x32x16_bf16(vb, pB, o1, 0, 0, 0);
        }
      }
    }
  }
  const float inv = 1.f / l_;
  short* op = O + (size_t)(qb + l31) * HIDN + h * HD;
  #pragma unroll
  for (int dt = 0; dt < 2; ++dt) {
    const f32x16& o = dt ? o1 : o0;
    #pragma unroll
    for (int g = 0; g < 4; ++g) {
      s16x4 st;
      st[0] = f2bf(o[g * 4 + 0] * inv);
      st[1] = f2bf(o[g * 4 + 1] * inv);
      st[2] = f2bf(o[g * 4 + 2] * inv);
      st[3] = f2bf(o[g * 4 + 3] * inv);
      *(s16x4*)(op + dt * 32 + g * 8 + hi * 4) = st;
    }
  }
}

// ---------------- out += P0 + P1 (split-K reduce) ----------------
__global__ __launch_bounds__(256) void reduce_kernel(float* __restrict__ out,
    const float* __restrict__ P) {
  const size_t n = (size_t)S_LEN * HIDN;
  size_t i = ((size_t)blockIdx.x * 256 + threadIdx.x) * 4;
  float4 o = *(float4*)(out + i);
  float4 a = *(const float4*)(P + i);
  float4 b = *(const float4*)(P + n + i);
  o.x += a.x + b.x; o.y += a.y + b.y; o.z += a.z + b.z; o.w += a.w + b.w;
  *(float4*)(out + i) = o;
}

extern "C" void kernel_launch(void* const* d_in, const int* in_sizes, int n_in,
                              void* d_out, int out_size, void* d_ws, size_t ws_size,
                              hipStream_t stream) {
  const float* hs   = (const float*)d_in[0];
  const float* cosb = (const float*)d_in[1];
  const float* sinb = (const float*)d_in[2];
  const float* wq   = (const float*)d_in[3];
  const float* wk   = (const float*)d_in[4];
  const float* wv   = (const float*)d_in[5];
  const float* wo   = (const float*)d_in[6];
  const float* wln1 = (const float*)d_in[7];
  const float* wln2 = (const float*)d_in[8];
  const float* wg   = (const float*)d_in[9];
  const float* wu   = (const float*)d_in[10];
  const float* wd   = (const float*)d_in[11];
  float* out = (float*)d_out;
  char* ws = (char*)d_ws;
  const size_t MB = 1024 * 1024;
  short* xn    = (short*)(ws);             //  8 MB bf16 [2048][2048]
  short* y     = (short*)(ws + 8 * MB);    //  8 MB
  short* attnO = (short*)(ws + 16 * MB);   //  8 MB
  short* qkv   = (short*)(ws + 24 * MB);   // 12.6 MB bf16 [2048][3072]
  short* g     = (short*)(ws + 37 * MB);   // 32 MB bf16 [2048][8192]
  short* Wbuf  = (short*)(ws + 69 * MB);   // 32 MB time-shared transposed weights
  float* P     = (float*)(ws);             // 32 MB split-K partials (aliases dead bufs)

  convT_kernel<<<dim3(32, 32), 256, 0, stream>>>(wq, Wbuf, HIDN, NH * HD);
  convT_kernel<<<dim3(32, 8),  256, 0, stream>>>(wk, Wbuf + (size_t)2048 * HIDN, HIDN, NKV * HD);
  convT_kernel<<<dim3(32, 8),  256, 0, stream>>>(wv, Wbuf + (size_t)2560 * HIDN, HIDN, NKV * HD);
  rmsnorm_kernel<<<S_LEN, 256, 0, stream>>>(hs, wln1, xn);
  gemm8p<0, 128><<<dim3(192, 1, 1), 512, 0, stream>>>(xn, Wbuf, qkv, nullptr, QKVN, HIDN, HIDN, 24);
  convT_kernel<<<dim3(32, 32), 256, 0, stream>>>(wo, Wbuf, NH * HD, HIDN);
  rope_kernel<<<(S_LEN * (NH + NKV) * 32) / 256, 256, 0, stream>>>(qkv, cosb, sinb);
  attn_kernel<<<NH * (S_LEN / 128), 256, 0, stream>>>(qkv, attnO);
  gemm_bt<1><<<dim3(16 * 16, 1), 256, 0, stream>>>(attnO, Wbuf, out, hs, S_LEN, HIDN, NH * HD, NH * HD, 16);
  rmsnorm_kernel<<<S_LEN, 256, 0, stream>>>(out, wln2, y);
  convT_kernel<<<dim3(32, 128), 256, 0, stream>>>(wg, Wbuf, HIDN, FFN);
  gemm8p<0, 256><<<dim3(256, 1, 1), 512, 0, stream>>>(y, Wbuf, g, nullptr, FFN, HIDN, HIDN, 32);
  convT_kernel<<<dim3(32, 128), 256, 0, stream>>>(wu, Wbuf, HIDN, FFN);
  gemm8p<2, 256><<<dim3(256, 1, 1), 512, 0, stream>>>(y, Wbuf, g, g, FFN, HIDN, HIDN, 32);
  convT_kernel<<<dim3(128, 32), 256, 0, stream>>>(wd, Wbuf, FFN, HIDN);
  gemm8p<3, 128><<<dim3(128, 1, 2), 512, 0, stream>>>(g, Wbuf, P, nullptr, HIDN, FFN, FFN / 2, 16);
  reduce_kernel<<<(S_LEN * HIDN) / 1024, 256, 0, stream>>>(out, P);
}